// Round 1
// baseline (391.123 us; speedup 1.0000x reference)
//
#include <hip/hip_runtime.h>

// TransformerBlock: B=8,S=196,D=768,H=12,HD=64,E=8,FF=3072. T = B*S = 1568 tokens.
//
// Key simplification (exact): k,v are broadcast across heads, so attention logits
// are constant over the softmax axis -> softmax is uniform -> attn_out = v tiled
// across heads. Wq/bq/Wk/bk/RoPE are dead code.
// MoE: top-1 expert per token = argmax of gating logits (softmax monotone).

typedef unsigned short u16;
typedef short bf16x8_t __attribute__((ext_vector_type(8)));
typedef short bf16x4_t __attribute__((ext_vector_type(4)));
typedef float f32x4_t  __attribute__((ext_vector_type(4)));

#define T_TOK 1568
#define DM 768
#define HD 64
#define FF 3072
#define NE 8

// workspace layout (all offsets 16B-aligned; total ~18.8 MB)
#define OFF_CNT   0
#define OFF_BUCK  256
#define OFF_V     (OFF_BUCK + NE*T_TOK*4)     // 50432
#define OFF_H1    (OFF_V + T_TOK*HD*4)        // 451840
#define OFF_H2    (OFF_H1 + T_TOK*DM*2)       // 2860288
#define OFF_X2    (OFF_H2 + T_TOK*DM*2)       // 5268736
#define OFF_HMID  (OFF_X2 + T_TOK*DM*4)       // 10085632

__device__ __forceinline__ float bf2f(u16 h) {
    unsigned u = ((unsigned)h) << 16;
    return __builtin_bit_cast(float, u);
}
__device__ __forceinline__ u16 f2bf(float f) {  // round-to-nearest-even
    unsigned u = __builtin_bit_cast(unsigned, f);
    unsigned r = (u + 0x7FFFu + ((u >> 16) & 1u)) >> 16;
    return (u16)r;
}
__device__ __forceinline__ float gelu_f(float x) {
    return 0.5f * x * (1.0f + erff(x * 0.70710678118654752440f));
}

// ---------------- K1: LN1 per token -> h1 (bf16) ----------------
__global__ __launch_bounds__(256) void k_ln1(const float* __restrict__ x,
                                             const float* __restrict__ g,
                                             const float* __restrict__ b,
                                             u16* __restrict__ h1) {
    int t = blockIdx.x, tid = threadIdx.x;
    const float* xr = x + (size_t)t * DM;
    float v0 = xr[tid], v1 = xr[tid + 256], v2 = xr[tid + 512];
    float s = v0 + v1 + v2;
#pragma unroll
    for (int m = 1; m < 64; m <<= 1) s += __shfl_xor(s, m);
    __shared__ float wr1[4], wr2[4];
    int lane = tid & 63, w = tid >> 6;
    if (lane == 0) wr1[w] = s;
    __syncthreads();
    float mu = (wr1[0] + wr1[1] + wr1[2] + wr1[3]) * (1.0f / DM);
    float d0 = v0 - mu, d1 = v1 - mu, d2 = v2 - mu;
    float vs = d0 * d0 + d1 * d1 + d2 * d2;
#pragma unroll
    for (int m = 1; m < 64; m <<= 1) vs += __shfl_xor(vs, m);
    if (lane == 0) wr2[w] = vs;
    __syncthreads();
    float var = (wr2[0] + wr2[1] + wr2[2] + wr2[3]) * (1.0f / DM);
    float rs = rsqrtf(var + 1e-5f);
    u16* hr = h1 + (size_t)t * DM;
    hr[tid]       = f2bf(d0 * rs * g[tid]       + b[tid]);
    hr[tid + 256] = f2bf(d1 * rs * g[tid + 256] + b[tid + 256]);
    hr[tid + 512] = f2bf(d2 * rs * g[tid + 512] + b[tid + 512]);
}

// ---------------- K2: v = h1 @ Wv + bv  (16 tokens per block) ----------------
__global__ __launch_bounds__(256) void k_vproj(const u16* __restrict__ h1,
                                               const float* __restrict__ Wv,
                                               const float* __restrict__ bv,
                                               float* __restrict__ vout) {
    __shared__ __align__(16) u16 h1s[16 * DM];    // 24 KB
    __shared__ float ps[4 * 16 * 64];             // 16 KB
    int tid = threadIdx.x, tb = blockIdx.x * 16;
    // stage 16 token rows of h1 (bf16) into LDS
#pragma unroll
    for (int j = 0; j < 6; j++) {
        int cid = tid + 256 * j;           // 1536 chunks of 16B
        int row = cid / 96, c = cid % 96;
        *(bf16x8_t*)&h1s[row * DM + c * 8] =
            *(const bf16x8_t*)&h1[(size_t)(tb + row) * DM + c * 8];
    }
    __syncthreads();
    int j = tid & 63, w = tid >> 6;        // wave w covers k in [w*192, w*192+192)
    float acc[16];
#pragma unroll
    for (int tt = 0; tt < 16; tt++) acc[tt] = 0.0f;
    const float* wp = Wv + (size_t)(w * 192) * HD + j;
    for (int kk = 0; kk < 192; kk += 4) {
        float w0 = wp[(size_t)(kk + 0) * HD];
        float w1 = wp[(size_t)(kk + 1) * HD];
        float w2 = wp[(size_t)(kk + 2) * HD];
        float w3 = wp[(size_t)(kk + 3) * HD];
        int kb = w * 192 + kk;
#pragma unroll
        for (int tt = 0; tt < 16; tt++) {
            bf16x4_t hh = *(const bf16x4_t*)&h1s[tt * DM + kb];   // LDS broadcast
            acc[tt] += bf2f((u16)hh[0]) * w0 + bf2f((u16)hh[1]) * w1 +
                       bf2f((u16)hh[2]) * w2 + bf2f((u16)hh[3]) * w3;
        }
    }
#pragma unroll
    for (int tt = 0; tt < 16; tt++) ps[(w * 16 + tt) * 64 + j] = acc[tt];
    __syncthreads();
    int tg = tid >> 6;
#pragma unroll
    for (int s2 = 0; s2 < 4; s2++) {
        int tt = tg * 4 + s2;
        float v = ps[tt * 64 + j] + ps[(16 + tt) * 64 + j] +
                  ps[(32 + tt) * 64 + j] + ps[(48 + tt) * 64 + j] + bv[j];
        vout[(size_t)(tb + tt) * HD + j] = v;
    }
}

// ------- K3: x2 = x + tile(v); LN2; h2(bf16); gating argmax; bucketize -------
__global__ __launch_bounds__(256) void k_x2ln2gate(
        const float* __restrict__ x, const float* __restrict__ vws,
        const float* __restrict__ g2, const float* __restrict__ b2g,
        const float* __restrict__ Wg, const float* __restrict__ bg,
        float* __restrict__ x2, u16* __restrict__ h2,
        int* __restrict__ cnt, int* __restrict__ buck) {
    __shared__ float wgs[NE * DM];      // transposed: wgs[e*768+c], 24 KB
    __shared__ float g2s[DM], b2s[DM];
    int tid = threadIdx.x, tb = blockIdx.x * 16;
    for (int idx = tid; idx < NE * DM; idx += 256) {
        int e = idx / DM, c = idx % DM;
        wgs[idx] = Wg[(size_t)c * NE + e];
    }
    for (int idx = tid; idx < DM; idx += 256) { g2s[idx] = g2[idx]; b2s[idx] = b2g[idx]; }
    __syncthreads();
    int lane = tid & 63, w = tid >> 6;
    for (int ttl = 0; ttl < 4; ttl++) {
        int t = tb + w * 4 + ttl;
        float vl = vws[(size_t)t * HD + lane];
        const float* xp = x + (size_t)t * DM;
        float* x2p = x2 + (size_t)t * DM;
        float xv[12];
        float s = 0.0f;
#pragma unroll
        for (int i = 0; i < 12; i++) {
            float q = xp[lane + 64 * i] + vl;   // v index = c % 64 == lane
            xv[i] = q; s += q;
            x2p[lane + 64 * i] = q;
        }
#pragma unroll
        for (int m = 1; m < 64; m <<= 1) s += __shfl_xor(s, m);
        float mu = s * (1.0f / DM);
        float vs = 0.0f;
#pragma unroll
        for (int i = 0; i < 12; i++) { float d = xv[i] - mu; vs += d * d; }
#pragma unroll
        for (int m = 1; m < 64; m <<= 1) vs += __shfl_xor(vs, m);
        float rs = rsqrtf(vs * (1.0f / DM) + 1e-5f);
        float le[NE];
#pragma unroll
        for (int e = 0; e < NE; e++) le[e] = 0.0f;
        u16* h2p = h2 + (size_t)t * DM;
#pragma unroll
        for (int i = 0; i < 12; i++) {
            int c = lane + 64 * i;
            float h = (xv[i] - mu) * rs * g2s[c] + b2s[c];
            h2p[c] = f2bf(h);
#pragma unroll
            for (int e = 0; e < NE; e++) le[e] += h * wgs[e * DM + c];
        }
#pragma unroll
        for (int e = 0; e < NE; e++) {
#pragma unroll
            for (int m = 1; m < 64; m <<= 1) le[e] += __shfl_xor(le[e], m);
        }
        if (lane == 0) {
            float best = le[0] + bg[0]; int be = 0;
#pragma unroll
            for (int e = 1; e < NE; e++) {
                float q = le[e] + bg[e];
                if (q > best) { best = q; be = e; }   // strict > == first-max (jnp.argmax)
            }
            int pos = atomicAdd(&cnt[be], 1);
            buck[be * T_TOK + pos] = t;
        }
    }
}

// ---------------- K4: grouped GEMM1 + gelu: hmid = gelu(h2 @ W1[e] + b1[e]) ----------------
// BM=256, BN=64, BK=32; 256 threads = 4 waves, wave -> 64-row strip x 64 cols.
__global__ __launch_bounds__(256, 2) void k_moe_gemm1(
        const u16* __restrict__ h2, const float* __restrict__ W1,
        const float* __restrict__ b1, const int* __restrict__ cnt,
        const int* __restrict__ buck, u16* __restrict__ hmid) {
    int nt = blockIdx.x, e = blockIdx.y, mt = blockIdx.z;
    int cnte = cnt[e];
    int m0 = mt * 256;
    if (m0 >= cnte) return;
    int n0 = nt * 64;
    const float* W1e = W1 + (size_t)e * DM * FF;
    __shared__ __align__(16) u16 As[256 * 40];   // 20 KB, row stride 40 halves (80B)
    __shared__ __align__(16) u16 Bs[64 * 40];    // 5 KB,  [n][k] transposed
    int tid = threadIdx.x, lane = tid & 63, wid = tid >> 6;

    int atok[4];
#pragma unroll
    for (int j = 0; j < 4; j++) {
        int cid = tid + 256 * j;
        int row = cid >> 2;
        int i = m0 + row;
        atok[j] = (i < cnte) ? buck[e * T_TOK + i] : -1;
    }
    f32x4_t acc[4][4];
#pragma unroll
    for (int mi = 0; mi < 4; mi++)
#pragma unroll
        for (int ni = 0; ni < 4; ni++) acc[mi][ni] = (f32x4_t){0.f, 0.f, 0.f, 0.f};

    for (int kt = 0; kt < DM / 32; kt++) {
        int k0 = kt * 32;
        __syncthreads();
        // stage A: 256x32 bf16 (gathered token rows)
#pragma unroll
        for (int j = 0; j < 4; j++) {
            int cid = tid + 256 * j;
            int row = cid >> 2, c = cid & 3;
            bf16x8_t v = {0, 0, 0, 0, 0, 0, 0, 0};
            if (atok[j] >= 0)
                v = *(const bf16x8_t*)&h2[(size_t)atok[j] * DM + k0 + c * 8];
            *(bf16x8_t*)&As[row * 40 + c * 8] = v;
        }
        // stage B: 32x64 fp32 -> bf16, transposed to [n][k]
        {
            int n = tid & 63, kh = tid >> 6;
            const float* bp = W1e + (size_t)(k0 + kh * 8) * FF + n0 + n;
            bf16x8_t pv;
#pragma unroll
            for (int kk = 0; kk < 8; kk++) pv[kk] = (short)f2bf(bp[(size_t)kk * FF]);
            *(bf16x8_t*)&Bs[n * 40 + kh * 8] = pv;
        }
        __syncthreads();
        int lr = lane & 15, q = lane >> 4;
        bf16x8_t af[4], bfr[4];
#pragma unroll
        for (int mi = 0; mi < 4; mi++)
            af[mi] = *(const bf16x8_t*)&As[(wid * 64 + mi * 16 + lr) * 40 + q * 8];
#pragma unroll
        for (int ni = 0; ni < 4; ni++)
            bfr[ni] = *(const bf16x8_t*)&Bs[(ni * 16 + lr) * 40 + q * 8];
#pragma unroll
        for (int mi = 0; mi < 4; mi++)
#pragma unroll
            for (int ni = 0; ni < 4; ni++)
                acc[mi][ni] = __builtin_amdgcn_mfma_f32_16x16x32_bf16(
                    af[mi], bfr[ni], acc[mi][ni], 0, 0, 0);
    }
    // epilogue: bias + gelu, scatter rows by token id
    int lr = lane & 15, q = lane >> 4;
    float bias[4];
#pragma unroll
    for (int ni = 0; ni < 4; ni++) bias[ni] = b1[(size_t)e * FF + n0 + ni * 16 + lr];
#pragma unroll
    for (int mi = 0; mi < 4; mi++) {
#pragma unroll
        for (int r = 0; r < 4; r++) {
            int i = m0 + wid * 64 + mi * 16 + q * 4 + r;
            if (i < cnte) {
                int t = buck[e * T_TOK + i];
                size_t base = (size_t)t * FF + n0;
#pragma unroll
                for (int ni = 0; ni < 4; ni++) {
                    float vv = acc[mi][ni][r] + bias[ni];
                    hmid[base + ni * 16 + lr] = f2bf(gelu_f(vv));
                }
            }
        }
    }
}

// ---------------- K5: grouped GEMM2 + residual: out = x2 + hmid @ W2[e] + b2[e] ----------------
// BM=128, BN=64, BK=32; wave -> 32-row strip x 64 cols.
__global__ __launch_bounds__(256, 2) void k_moe_gemm2(
        const u16* __restrict__ hmid, const float* __restrict__ W2,
        const float* __restrict__ b2, const int* __restrict__ cnt,
        const int* __restrict__ buck, const float* __restrict__ x2,
        float* __restrict__ out) {
    int nt = blockIdx.x, e = blockIdx.y, mt = blockIdx.z;
    int cnte = cnt[e];
    int m0 = mt * 128;
    if (m0 >= cnte) return;
    int n0 = nt * 64;
    const float* W2e = W2 + (size_t)e * FF * DM;
    __shared__ __align__(16) u16 As[128 * 40];   // 10 KB
    __shared__ __align__(16) u16 Bs[64 * 40];    // 5 KB
    int tid = threadIdx.x, lane = tid & 63, wid = tid >> 6;

    int atok[2];
#pragma unroll
    for (int j = 0; j < 2; j++) {
        int cid = tid + 256 * j;
        int row = cid >> 2;
        int i = m0 + row;
        atok[j] = (i < cnte) ? buck[e * T_TOK + i] : -1;
    }
    f32x4_t acc[2][4];
#pragma unroll
    for (int mi = 0; mi < 2; mi++)
#pragma unroll
        for (int ni = 0; ni < 4; ni++) acc[mi][ni] = (f32x4_t){0.f, 0.f, 0.f, 0.f};

    for (int kt = 0; kt < FF / 32; kt++) {
        int k0 = kt * 32;
        __syncthreads();
#pragma unroll
        for (int j = 0; j < 2; j++) {
            int cid = tid + 256 * j;
            int row = cid >> 2, c = cid & 3;
            bf16x8_t v = {0, 0, 0, 0, 0, 0, 0, 0};
            if (atok[j] >= 0)
                v = *(const bf16x8_t*)&hmid[(size_t)atok[j] * FF + k0 + c * 8];
            *(bf16x8_t*)&As[row * 40 + c * 8] = v;
        }
        {
            int n = tid & 63, kh = tid >> 6;
            const float* bp = W2e + (size_t)(k0 + kh * 8) * DM + n0 + n;
            bf16x8_t pv;
#pragma unroll
            for (int kk = 0; kk < 8; kk++) pv[kk] = (short)f2bf(bp[(size_t)kk * DM]);
            *(bf16x8_t*)&Bs[n * 40 + kh * 8] = pv;
        }
        __syncthreads();
        int lr = lane & 15, q = lane >> 4;
        bf16x8_t af[2], bfr[4];
#pragma unroll
        for (int mi = 0; mi < 2; mi++)
            af[mi] = *(const bf16x8_t*)&As[(wid * 32 + mi * 16 + lr) * 40 + q * 8];
#pragma unroll
        for (int ni = 0; ni < 4; ni++)
            bfr[ni] = *(const bf16x8_t*)&Bs[(ni * 16 + lr) * 40 + q * 8];
#pragma unroll
        for (int mi = 0; mi < 2; mi++)
#pragma unroll
            for (int ni = 0; ni < 4; ni++)
                acc[mi][ni] = __builtin_amdgcn_mfma_f32_16x16x32_bf16(
                    af[mi], bfr[ni], acc[mi][ni], 0, 0, 0);
    }
    int lr = lane & 15, q = lane >> 4;
    float bias[4];
#pragma unroll
    for (int ni = 0; ni < 4; ni++) bias[ni] = b2[(size_t)e * DM + n0 + ni * 16 + lr];
#pragma unroll
    for (int mi = 0; mi < 2; mi++) {
#pragma unroll
        for (int r = 0; r < 4; r++) {
            int i = m0 + wid * 32 + mi * 16 + q * 4 + r;
            if (i < cnte) {
                int t = buck[e * T_TOK + i];
                size_t base = (size_t)t * DM + n0;
#pragma unroll
                for (int ni = 0; ni < 4; ni++)
                    out[base + ni * 16 + lr] =
                        acc[mi][ni][r] + bias[ni] + x2[base + ni * 16 + lr];
            }
        }
    }
}

extern "C" void kernel_launch(void* const* d_in, const int* in_sizes, int n_in,
                              void* d_out, int out_size, void* d_ws, size_t ws_size,
                              hipStream_t stream) {
    const float* x    = (const float*)d_in[0];
    const float* ln1g = (const float*)d_in[1];
    const float* ln1b = (const float*)d_in[2];
    // d_in[3..6] = Wq,bq,Wk,bk: dead code (see header comment)
    const float* Wv   = (const float*)d_in[7];
    const float* bv   = (const float*)d_in[8];
    const float* ln2g = (const float*)d_in[9];
    const float* ln2b = (const float*)d_in[10];
    const float* Wg   = (const float*)d_in[11];
    const float* bg   = (const float*)d_in[12];
    const float* W1   = (const float*)d_in[13];
    const float* b1   = (const float*)d_in[14];
    const float* W2   = (const float*)d_in[15];
    const float* b2   = (const float*)d_in[16];

    char* ws = (char*)d_ws;
    int*   cnt  = (int*)(ws + OFF_CNT);
    int*   buck = (int*)(ws + OFF_BUCK);
    float* vws  = (float*)(ws + OFF_V);
    u16*   h1   = (u16*)(ws + OFF_H1);
    u16*   h2   = (u16*)(ws + OFF_H2);
    float* x2   = (float*)(ws + OFF_X2);
    u16*   hmid = (u16*)(ws + OFF_HMID);
    float* out  = (float*)d_out;

    hipMemsetAsync(cnt, 0, NE * sizeof(int), stream);
    k_ln1<<<T_TOK, 256, 0, stream>>>(x, ln1g, ln1b, h1);
    k_vproj<<<T_TOK / 16, 256, 0, stream>>>(h1, Wv, bv, vws);
    k_x2ln2gate<<<T_TOK / 16, 256, 0, stream>>>(x, vws, ln2g, ln2b, Wg, bg,
                                                x2, h2, cnt, buck);
    k_moe_gemm1<<<dim3(FF / 64, NE, 7), 256, 0, stream>>>(h2, W1, b1, cnt, buck, hmid);
    k_moe_gemm2<<<dim3(DM / 64, NE, 13), 256, 0, stream>>>(hmid, W2, b2, cnt, buck, x2, out);
}

// Round 2
// 299.055 us; speedup vs baseline: 1.3079x; 1.3079x over previous
//
#include <hip/hip_runtime.h>

// TransformerBlock: B=8,S=196,D=768,H=12,HD=64,E=8,FF=3072. T = B*S = 1568 tokens.
//
// Exact simplifications:
//  - attention: k,v broadcast across heads -> logits constant over softmax axis
//    -> softmax uniform -> attn_out = tile(v). Wq/bq/Wk/bk/RoPE are dead code.
//  - MoE top-1 = argmax of gating logits (softmax monotone).
//
// R1 structure: out is pre-initialized with x2 + b2[expert] in the gate kernel;
// GEMM2 is split-K x4 and atomicAdds fp32 partials into out. Both MoE GEMMs:
// BM=128, BN=64, BK=64, register prefetch of next K-tile overlapping MFMA.

typedef unsigned short u16;
typedef short bf16x8_t __attribute__((ext_vector_type(8)));
typedef short bf16x4_t __attribute__((ext_vector_type(4)));
typedef float f32x4_t  __attribute__((ext_vector_type(4)));

#define T_TOK 1568
#define DM 768
#define HD 64
#define FF 3072
#define NE 8

// workspace layout (16B-aligned offsets; ~14.9 MB total)
#define OFF_CNT   0
#define OFF_BUCK  256
#define OFF_V     (OFF_BUCK + NE*T_TOK*4)
#define OFF_H1    (OFF_V + T_TOK*HD*4)
#define OFF_H2    (OFF_H1 + T_TOK*DM*2)
#define OFF_HMID  (OFF_H2 + T_TOK*DM*2)

__device__ __forceinline__ float bf2f(u16 h) {
    unsigned u = ((unsigned)h) << 16;
    return __builtin_bit_cast(float, u);
}
__device__ __forceinline__ u16 f2bf(float f) {  // round-to-nearest-even
    unsigned u = __builtin_bit_cast(unsigned, f);
    unsigned r = (u + 0x7FFFu + ((u >> 16) & 1u)) >> 16;
    return (u16)r;
}
__device__ __forceinline__ float gelu_f(float x) {
    return 0.5f * x * (1.0f + erff(x * 0.70710678118654752440f));
}

// ---------------- K1: LN1 per token -> h1 (bf16) ----------------
__global__ __launch_bounds__(256) void k_ln1(const float* __restrict__ x,
                                             const float* __restrict__ g,
                                             const float* __restrict__ b,
                                             u16* __restrict__ h1) {
    int t = blockIdx.x, tid = threadIdx.x;
    const float* xr = x + (size_t)t * DM;
    float v0 = xr[tid], v1 = xr[tid + 256], v2 = xr[tid + 512];
    float s = v0 + v1 + v2;
#pragma unroll
    for (int m = 1; m < 64; m <<= 1) s += __shfl_xor(s, m);
    __shared__ float wr1[4], wr2[4];
    int lane = tid & 63, w = tid >> 6;
    if (lane == 0) wr1[w] = s;
    __syncthreads();
    float mu = (wr1[0] + wr1[1] + wr1[2] + wr1[3]) * (1.0f / DM);
    float d0 = v0 - mu, d1 = v1 - mu, d2 = v2 - mu;
    float vs = d0 * d0 + d1 * d1 + d2 * d2;
#pragma unroll
    for (int m = 1; m < 64; m <<= 1) vs += __shfl_xor(vs, m);
    if (lane == 0) wr2[w] = vs;
    __syncthreads();
    float var = (wr2[0] + wr2[1] + wr2[2] + wr2[3]) * (1.0f / DM);
    float rs = rsqrtf(var + 1e-5f);
    u16* hr = h1 + (size_t)t * DM;
    hr[tid]       = f2bf(d0 * rs * g[tid]       + b[tid]);
    hr[tid + 256] = f2bf(d1 * rs * g[tid + 256] + b[tid + 256]);
    hr[tid + 512] = f2bf(d2 * rs * g[tid + 512] + b[tid + 512]);
}

// ---------------- K2: v = h1 @ Wv + bv  (8 tokens per block) ----------------
__global__ __launch_bounds__(256) void k_vproj(const u16* __restrict__ h1,
                                               const float* __restrict__ Wv,
                                               const float* __restrict__ bv,
                                               float* __restrict__ vout) {
    __shared__ __align__(16) u16 h1s[8 * DM];     // 12 KB
    __shared__ float ps[4 * 8 * 64];              // 8 KB
    int tid = threadIdx.x, tb = blockIdx.x * 8;
#pragma unroll
    for (int j = 0; j < 3; j++) {
        int cid = tid + 256 * j;           // 768 chunks of 16B
        int row = cid / 96, c = cid % 96;
        *(bf16x8_t*)&h1s[row * DM + c * 8] =
            *(const bf16x8_t*)&h1[(size_t)(tb + row) * DM + c * 8];
    }
    __syncthreads();
    int j = tid & 63, w = tid >> 6;        // wave w covers k in [w*192, w*192+192)
    float acc[8];
#pragma unroll
    for (int tt = 0; tt < 8; tt++) acc[tt] = 0.0f;
    const float* wp = Wv + (size_t)(w * 192) * HD + j;
    for (int kk = 0; kk < 192; kk += 4) {
        float w0 = wp[(size_t)(kk + 0) * HD];
        float w1 = wp[(size_t)(kk + 1) * HD];
        float w2 = wp[(size_t)(kk + 2) * HD];
        float w3 = wp[(size_t)(kk + 3) * HD];
        int kb = w * 192 + kk;
#pragma unroll
        for (int tt = 0; tt < 8; tt++) {
            bf16x4_t hh = *(const bf16x4_t*)&h1s[tt * DM + kb];
            acc[tt] += bf2f((u16)hh[0]) * w0 + bf2f((u16)hh[1]) * w1 +
                       bf2f((u16)hh[2]) * w2 + bf2f((u16)hh[3]) * w3;
        }
    }
#pragma unroll
    for (int tt = 0; tt < 8; tt++) ps[(w * 8 + tt) * 64 + j] = acc[tt];
    __syncthreads();
    int tg = tid >> 6;
#pragma unroll
    for (int s2 = 0; s2 < 2; s2++) {
        int tt = tg * 2 + s2;
        float v = ps[tt * 64 + j] + ps[(8 + tt) * 64 + j] +
                  ps[(16 + tt) * 64 + j] + ps[(24 + tt) * 64 + j] + bv[j];
        vout[(size_t)(tb + tt) * HD + j] = v;
    }
}

// --- K3: x2 = x + tile(v); LN2 -> h2(bf16); gate argmax; bucketize;
//     out init = x2 + b2[expert]  (8 tokens per block) ---
__global__ __launch_bounds__(256) void k_x2ln2gate(
        const float* __restrict__ x, const float* __restrict__ vws,
        const float* __restrict__ g2, const float* __restrict__ b2g,
        const float* __restrict__ Wg, const float* __restrict__ bg,
        const float* __restrict__ b2moe,
        u16* __restrict__ h2, float* __restrict__ out,
        int* __restrict__ cnt, int* __restrict__ buck) {
    __shared__ float wgs[NE * DM];      // transposed: wgs[e*768+c], 24 KB
    __shared__ float g2s[DM], b2s[DM];
    int tid = threadIdx.x, tb = blockIdx.x * 8;
    for (int idx = tid; idx < NE * DM; idx += 256) {
        int e = idx / DM, c = idx % DM;
        wgs[idx] = Wg[(size_t)c * NE + e];
    }
    for (int idx = tid; idx < DM; idx += 256) { g2s[idx] = g2[idx]; b2s[idx] = b2g[idx]; }
    __syncthreads();
    int lane = tid & 63, w = tid >> 6;
    for (int ttl = 0; ttl < 2; ttl++) {
        int t = tb + w * 2 + ttl;
        float vl = vws[(size_t)t * HD + lane];
        const float* xp = x + (size_t)t * DM;
        float xv[12];
        float s = 0.0f;
#pragma unroll
        for (int i = 0; i < 12; i++) {
            float q = xp[lane + 64 * i] + vl;   // v col index = c % 64 == lane
            xv[i] = q; s += q;
        }
#pragma unroll
        for (int m = 1; m < 64; m <<= 1) s += __shfl_xor(s, m);
        float mu = s * (1.0f / DM);
        float vs = 0.0f;
#pragma unroll
        for (int i = 0; i < 12; i++) { float d = xv[i] - mu; vs += d * d; }
#pragma unroll
        for (int m = 1; m < 64; m <<= 1) vs += __shfl_xor(vs, m);
        float rs = rsqrtf(vs * (1.0f / DM) + 1e-5f);
        float le[NE];
#pragma unroll
        for (int e = 0; e < NE; e++) le[e] = 0.0f;
        u16* h2p = h2 + (size_t)t * DM;
#pragma unroll
        for (int i = 0; i < 12; i++) {
            int c = lane + 64 * i;
            float h = (xv[i] - mu) * rs * g2s[c] + b2s[c];
            h2p[c] = f2bf(h);
#pragma unroll
            for (int e = 0; e < NE; e++) le[e] += h * wgs[e * DM + c];
        }
#pragma unroll
        for (int e = 0; e < NE; e++) {
#pragma unroll
            for (int m = 1; m < 64; m <<= 1) le[e] += __shfl_xor(le[e], m);
        }
        // all lanes hold bitwise-identical le[] (butterfly) -> uniform argmax
        float best = le[0] + bg[0]; int be = 0;
#pragma unroll
        for (int e = 1; e < NE; e++) {
            float q = le[e] + bg[e];
            if (q > best) { best = q; be = e; }   // strict > == first-max (jnp.argmax)
        }
        if (lane == 0) {
            int pos = atomicAdd(&cnt[be], 1);
            buck[be * T_TOK + pos] = t;
        }
        // out init: x2 + b2[be]  (gemm2 atomicAdds the MoE matmul on top)
        float* op = out + (size_t)t * DM;
        const float* bp = b2moe + (size_t)be * DM;
#pragma unroll
        for (int i = 0; i < 12; i++) {
            int c = lane + 64 * i;
            op[c] = xv[i] + bp[c];
        }
    }
}

// ---------------- K4: grouped GEMM1 + gelu: hmid = gelu(h2 @ W1[e] + b1[e]) ----------------
// BM=128, BN=64, BK=64; 4 waves, wave -> 32-row strip x 64 cols.
// Register prefetch of next K-tile overlaps ds_read+MFMA of current tile.
__global__ __launch_bounds__(256, 2) void k_moe_gemm1(
        const u16* __restrict__ h2, const float* __restrict__ W1,
        const float* __restrict__ b1, const int* __restrict__ cnt,
        const int* __restrict__ buck, u16* __restrict__ hmid) {
    int nt = blockIdx.x, e = blockIdx.y, mt = blockIdx.z;
    int cnte = cnt[e];
    int m0 = mt * 128;
    if (m0 >= cnte) return;
    int n0 = nt * 64;
    const float* W1e = W1 + (size_t)e * DM * FF;
    __shared__ __align__(16) u16 As[128 * 72];   // 18 KB
    __shared__ __align__(16) u16 Bs[64 * 72];    // 9 KB, [n][k]
    int tid = threadIdx.x, lane = tid & 63, wid = tid >> 6;

    // A staging map: chunk cid=tid+256j -> row=(tid>>3)+32j, col-chunk c=tid&7
    int arow = tid >> 3, ac = tid & 7;
    int atok[4];
#pragma unroll
    for (int j = 0; j < 4; j++) {
        int i = m0 + arow + 32 * j;
        atok[j] = (i < cnte) ? buck[e * T_TOK + i] : -1;
    }
    // B staging map: n=tid&63, k-group kg=tid>>6 covers k rows kg*16..kg*16+15
    int bn = tid & 63, bkg = tid >> 6;

    f32x4_t acc[2][4];
#pragma unroll
    for (int mi = 0; mi < 2; mi++)
#pragma unroll
        for (int ni = 0; ni < 4; ni++) acc[mi][ni] = (f32x4_t){0.f, 0.f, 0.f, 0.f};

    bf16x8_t a_pre[4];
    float b_pre[16];
    // prefetch kt=0
#pragma unroll
    for (int j = 0; j < 4; j++) {
        bf16x8_t v = {0, 0, 0, 0, 0, 0, 0, 0};
        if (atok[j] >= 0) v = *(const bf16x8_t*)&h2[(size_t)atok[j] * DM + ac * 8];
        a_pre[j] = v;
    }
    {
        const float* bp = W1e + (size_t)(bkg * 16) * FF + n0 + bn;
#pragma unroll
        for (int kk = 0; kk < 16; kk++) b_pre[kk] = bp[(size_t)kk * FF];
    }

    const int NK = DM / 64;   // 12
    for (int kt = 0; kt < NK; kt++) {
        __syncthreads();
        // regs -> LDS (compiler inserts vmcnt wait here)
#pragma unroll
        for (int j = 0; j < 4; j++)
            *(bf16x8_t*)&As[(arow + 32 * j) * 72 + ac * 8] = a_pre[j];
        {
            bf16x8_t p0, p1;
#pragma unroll
            for (int kk = 0; kk < 8; kk++) {
                p0[kk] = (short)f2bf(b_pre[kk]);
                p1[kk] = (short)f2bf(b_pre[kk + 8]);
            }
            *(bf16x8_t*)&Bs[bn * 72 + bkg * 16] = p0;
            *(bf16x8_t*)&Bs[bn * 72 + bkg * 16 + 8] = p1;
        }
        __syncthreads();
        // issue prefetch for kt+1 (overlaps MFMA below)
        if (kt + 1 < NK) {
            int k0 = (kt + 1) * 64;
#pragma unroll
            for (int j = 0; j < 4; j++) {
                bf16x8_t v = {0, 0, 0, 0, 0, 0, 0, 0};
                if (atok[j] >= 0)
                    v = *(const bf16x8_t*)&h2[(size_t)atok[j] * DM + k0 + ac * 8];
                a_pre[j] = v;
            }
            const float* bp = W1e + (size_t)(k0 + bkg * 16) * FF + n0 + bn;
#pragma unroll
            for (int kk = 0; kk < 16; kk++) b_pre[kk] = bp[(size_t)kk * FF];
        }
        int lr = lane & 15, q = lane >> 4;
#pragma unroll
        for (int s = 0; s < 2; s++) {
            bf16x8_t af[2], bfr[4];
#pragma unroll
            for (int mi = 0; mi < 2; mi++)
                af[mi] = *(const bf16x8_t*)&As[(wid * 32 + mi * 16 + lr) * 72 + s * 32 + q * 8];
#pragma unroll
            for (int ni = 0; ni < 4; ni++)
                bfr[ni] = *(const bf16x8_t*)&Bs[(ni * 16 + lr) * 72 + s * 32 + q * 8];
#pragma unroll
            for (int mi = 0; mi < 2; mi++)
#pragma unroll
                for (int ni = 0; ni < 4; ni++)
                    acc[mi][ni] = __builtin_amdgcn_mfma_f32_16x16x32_bf16(
                        af[mi], bfr[ni], acc[mi][ni], 0, 0, 0);
        }
    }
    // epilogue: bias + gelu, scatter by token id
    int lr = lane & 15, q = lane >> 4;
    float bias[4];
#pragma unroll
    for (int ni = 0; ni < 4; ni++) bias[ni] = b1[(size_t)e * FF + n0 + ni * 16 + lr];
#pragma unroll
    for (int mi = 0; mi < 2; mi++) {
#pragma unroll
        for (int r = 0; r < 4; r++) {
            int i = m0 + wid * 32 + mi * 16 + q * 4 + r;
            if (i < cnte) {
                int t = buck[e * T_TOK + i];
                size_t base = (size_t)t * FF + n0;
#pragma unroll
                for (int ni = 0; ni < 4; ni++) {
                    float vv = acc[mi][ni][r] + bias[ni];
                    hmid[base + ni * 16 + lr] = f2bf(gelu_f(vv));
                }
            }
        }
    }
}

// ---------------- K5: grouped GEMM2 split-K x4: out += hmid @ W2[e] ----------------
// BM=128, BN=64, BK=64, K-chunk = FF/4 = 768. z = mt*4 + kc.
__global__ __launch_bounds__(256, 2) void k_moe_gemm2(
        const u16* __restrict__ hmid, const float* __restrict__ W2,
        const int* __restrict__ cnt, const int* __restrict__ buck,
        float* __restrict__ out) {
    int nt = blockIdx.x, e = blockIdx.y, z = blockIdx.z;
    int kc = z & 3, mt = z >> 2;
    int cnte = cnt[e];
    int m0 = mt * 128;
    if (m0 >= cnte) return;
    int n0 = nt * 64;
    int kbase = kc * (FF / 4);
    const float* W2e = W2 + (size_t)e * FF * DM;
    __shared__ __align__(16) u16 As[128 * 72];
    __shared__ __align__(16) u16 Bs[64 * 72];
    int tid = threadIdx.x, lane = tid & 63, wid = tid >> 6;

    int arow = tid >> 3, ac = tid & 7;
    int atok[4];
#pragma unroll
    for (int j = 0; j < 4; j++) {
        int i = m0 + arow + 32 * j;
        atok[j] = (i < cnte) ? buck[e * T_TOK + i] : -1;
    }
    int bn = tid & 63, bkg = tid >> 6;

    f32x4_t acc[2][4];
#pragma unroll
    for (int mi = 0; mi < 2; mi++)
#pragma unroll
        for (int ni = 0; ni < 4; ni++) acc[mi][ni] = (f32x4_t){0.f, 0.f, 0.f, 0.f};

    bf16x8_t a_pre[4];
    float b_pre[16];
#pragma unroll
    for (int j = 0; j < 4; j++) {
        bf16x8_t v = {0, 0, 0, 0, 0, 0, 0, 0};
        if (atok[j] >= 0)
            v = *(const bf16x8_t*)&hmid[(size_t)atok[j] * FF + kbase + ac * 8];
        a_pre[j] = v;
    }
    {
        const float* bp = W2e + (size_t)(kbase + bkg * 16) * DM + n0 + bn;
#pragma unroll
        for (int kk = 0; kk < 16; kk++) b_pre[kk] = bp[(size_t)kk * DM];
    }

    const int NK = (FF / 4) / 64;   // 12
    for (int kt = 0; kt < NK; kt++) {
        __syncthreads();
#pragma unroll
        for (int j = 0; j < 4; j++)
            *(bf16x8_t*)&As[(arow + 32 * j) * 72 + ac * 8] = a_pre[j];
        {
            bf16x8_t p0, p1;
#pragma unroll
            for (int kk = 0; kk < 8; kk++) {
                p0[kk] = (short)f2bf(b_pre[kk]);
                p1[kk] = (short)f2bf(b_pre[kk + 8]);
            }
            *(bf16x8_t*)&Bs[bn * 72 + bkg * 16] = p0;
            *(bf16x8_t*)&Bs[bn * 72 + bkg * 16 + 8] = p1;
        }
        __syncthreads();
        if (kt + 1 < NK) {
            int k0 = kbase + (kt + 1) * 64;
#pragma unroll
            for (int j = 0; j < 4; j++) {
                bf16x8_t v = {0, 0, 0, 0, 0, 0, 0, 0};
                if (atok[j] >= 0)
                    v = *(const bf16x8_t*)&hmid[(size_t)atok[j] * FF + k0 + ac * 8];
                a_pre[j] = v;
            }
            const float* bp = W2e + (size_t)(k0 + bkg * 16) * DM + n0 + bn;
#pragma unroll
            for (int kk = 0; kk < 16; kk++) b_pre[kk] = bp[(size_t)kk * DM];
        }
        int lr = lane & 15, q = lane >> 4;
#pragma unroll
        for (int s = 0; s < 2; s++) {
            bf16x8_t af[2], bfr[4];
#pragma unroll
            for (int mi = 0; mi < 2; mi++)
                af[mi] = *(const bf16x8_t*)&As[(wid * 32 + mi * 16 + lr) * 72 + s * 32 + q * 8];
#pragma unroll
            for (int ni = 0; ni < 4; ni++)
                bfr[ni] = *(const bf16x8_t*)&Bs[(ni * 16 + lr) * 72 + s * 32 + q * 8];
#pragma unroll
            for (int mi = 0; mi < 2; mi++)
#pragma unroll
                for (int ni = 0; ni < 4; ni++)
                    acc[mi][ni] = __builtin_amdgcn_mfma_f32_16x16x32_bf16(
                        af[mi], bfr[ni], acc[mi][ni], 0, 0, 0);
        }
    }
    // epilogue: atomicAdd partials into out (out pre-initialized with x2 + b2[e])
    int lr = lane & 15, q = lane >> 4;
#pragma unroll
    for (int mi = 0; mi < 2; mi++) {
#pragma unroll
        for (int r = 0; r < 4; r++) {
            int i = m0 + wid * 32 + mi * 16 + q * 4 + r;
            if (i < cnte) {
                int t = buck[e * T_TOK + i];
                size_t base = (size_t)t * DM + n0;
#pragma unroll
                for (int ni = 0; ni < 4; ni++)
                    atomicAdd(&out[base + ni * 16 + lr], acc[mi][ni][r]);
            }
        }
    }
}

extern "C" void kernel_launch(void* const* d_in, const int* in_sizes, int n_in,
                              void* d_out, int out_size, void* d_ws, size_t ws_size,
                              hipStream_t stream) {
    const float* x    = (const float*)d_in[0];
    const float* ln1g = (const float*)d_in[1];
    const float* ln1b = (const float*)d_in[2];
    // d_in[3..6] = Wq,bq,Wk,bk: dead code
    const float* Wv   = (const float*)d_in[7];
    const float* bv   = (const float*)d_in[8];
    const float* ln2g = (const float*)d_in[9];
    const float* ln2b = (const float*)d_in[10];
    const float* Wg   = (const float*)d_in[11];
    const float* bg   = (const float*)d_in[12];
    const float* W1   = (const float*)d_in[13];
    const float* b1   = (const float*)d_in[14];
    const float* W2   = (const float*)d_in[15];
    const float* b2   = (const float*)d_in[16];

    char* ws = (char*)d_ws;
    int*   cnt  = (int*)(ws + OFF_CNT);
    int*   buck = (int*)(ws + OFF_BUCK);
    float* vws  = (float*)(ws + OFF_V);
    u16*   h1   = (u16*)(ws + OFF_H1);
    u16*   h2   = (u16*)(ws + OFF_H2);
    u16*   hmid = (u16*)(ws + OFF_HMID);
    float* out  = (float*)d_out;

    hipMemsetAsync(cnt, 0, NE * sizeof(int), stream);
    k_ln1<<<T_TOK, 256, 0, stream>>>(x, ln1g, ln1b, h1);
    k_vproj<<<T_TOK / 8, 256, 0, stream>>>(h1, Wv, bv, vws);
    k_x2ln2gate<<<T_TOK / 8, 256, 0, stream>>>(x, vws, ln2g, ln2b, Wg, bg, b2,
                                               h2, out, cnt, buck);
    k_moe_gemm1<<<dim3(FF / 64, NE, 13), 256, 0, stream>>>(h2, W1, b1, cnt, buck, hmid);
    k_moe_gemm2<<<dim3(DM / 64, NE, 52), 256, 0, stream>>>(hmid, W2, cnt, buck, out);
}